// Round 9
// baseline (46.060 us; speedup 1.0000x reference)
//
#include <hip/hip_runtime.h>
#include <hip/hip_bf16.h>

// Fused MPNN layer, B=256, N=81, H=128, E=1620 — single-kernel MFMA bf16.
//   P = X @ Wm1[:H],  Q' = X @ Wm1[H:] + bm1
//   Hsum[t] = sum_{e: tgt=t} relu(P[src_e] + Q'[t])
//   agg = (Hsum@Wm2 + deg*bm2)/max(deg,1)
//   h2  = relu(X@Wu1[:H] + agg@Wu1[H:] + bu1)
//   x   = X + h2@Wu2 + bu2 ;  out = LayerNorm(x)*gamma + beta
// ONE launch, grid 256 x 1024 (16 waves). Per block: ballot-CSR (~0.7us),
// B-fragments converted on the fly from fp32 weights (L2-resident),
// 4 GEMM phases, residual re-read from global (L2-hot), LN.

#define NN 81
#define HH 128
#define EE 1620
#define NCHK 26                          // ceil(EE/64)
#define MPAD 96

// LDS layout (bytes)
#define XB_OFF   0                       // bf16 swz [96][128]  24576
#define BP_OFF   24576                   // bf16 swz [96][128]  24576
#define BQ_OFF   49152                   // bf16 swz [96][128]  24576
#define CSRL_OFF 73728                   // int[1620]            6480
#define OFFL_OFF 80208                   // int[82]               328
#define BIAS_OFF 80536                   // float[6][128]        3072
#define SCR_OFF  83608                   // CSR scratch ints     28712
#define L_BYTES  112320
// xout fp32[81][128] (41472 B) aliases [0, 48K) = Xb+bufP (both dead at GEMM D)

typedef __attribute__((ext_vector_type(8))) short bf16x8;
typedef __attribute__((ext_vector_type(8))) unsigned short ushort8v;
typedef __attribute__((ext_vector_type(4))) float f32x4;

__device__ __forceinline__ unsigned short f2b(float f) {
  union { float f; unsigned u; } v; v.f = f;
  unsigned r = v.u + 0x7fffu + ((v.u >> 16) & 1u);
  return (unsigned short)(r >> 16);
}
__device__ __forceinline__ float b2f(unsigned short h) {
  union { unsigned u; float f; } v; v.u = ((unsigned)h) << 16;
  return v.f;
}
__device__ __forceinline__ unsigned f2b2(float x, float y) {  // packed RNE pair
  float2 f; f.x = x; f.y = y;
  union { __hip_bfloat162 h; unsigned u; } v;
  v.h = __float22bfloat162_rn(f);
  return v.u;
}
__device__ __forceinline__ unsigned swzu(int r, int laneb) {
  return ((unsigned)(r * 256 + laneb)) ^ ((unsigned)((r & 7) << 4));
}

// B-fragment (16x16x32 layout) straight from row-major fp32 W[k][c], converted.
__device__ __forceinline__ void loadB4G(const float* __restrict__ W, int nt0, int lane,
                                        bf16x8 (&Bf)[4]) {
  const int c  = nt0 * 16 + (lane & 15);
  const int kb = (lane >> 4) * 8;
#pragma unroll
  for (int ks = 0; ks < 4; ++ks) {
    const float* p = W + (ks * 32 + kb) * HH + c;
    union { bf16x8 v; uint4 u; } r;
    r.u.x = f2b2(p[0],      p[HH]);
    r.u.y = f2b2(p[2 * HH], p[3 * HH]);
    r.u.z = f2b2(p[4 * HH], p[5 * HH]);
    r.u.w = f2b2(p[6 * HH], p[7 * HH]);
    Bf[ks] = r.v;
  }
}

// 3-Mtile GEMM: acc += A(LDS, swz, rowbase)@Bf
__device__ __forceinline__ void gemm3(const char* Ab, int rowbase,
                                      const bf16x8 (&Bf)[4], int lane, f32x4 (&acc)[3]) {
  const int rl = lane & 15;
  const int kb = (lane >> 4) * 16;
  const unsigned swz = (unsigned)((rl & 7) << 4);
#pragma unroll
  for (int ks = 0; ks < 4; ++ks)
#pragma unroll
    for (int mm = 0; mm < 3; ++mm) {
      const int r = rowbase + mm * 16 + rl;
      const unsigned byte = (unsigned)(r * 256) + (((unsigned)(ks * 64 + kb)) ^ swz);
      bf16x8 a = *(const bf16x8*)(Ab + byte);
      acc[mm] = __builtin_amdgcn_mfma_f32_16x16x32_bf16(a, Bf[ks], acc[mm], 0, 0, 0);
    }
}

// dual-B, shared A reads
__device__ __forceinline__ void gemm3x2(const char* Ab, int rowbase,
                                        const bf16x8 (&B0)[4], const bf16x8 (&B1)[4],
                                        int lane, f32x4 (&a0)[3], f32x4 (&a1)[3]) {
  const int rl = lane & 15;
  const int kb = (lane >> 4) * 16;
  const unsigned swz = (unsigned)((rl & 7) << 4);
#pragma unroll
  for (int ks = 0; ks < 4; ++ks)
#pragma unroll
    for (int mm = 0; mm < 3; ++mm) {
      const int r = rowbase + mm * 16 + rl;
      const unsigned byte = (unsigned)(r * 256) + (((unsigned)(ks * 64 + kb)) ^ swz);
      bf16x8 a = *(const bf16x8*)(Ab + byte);
      a0[mm] = __builtin_amdgcn_mfma_f32_16x16x32_bf16(a, B0[ks], a0[mm], 0, 0, 0);
      a1[mm] = __builtin_amdgcn_mfma_f32_16x16x32_bf16(a, B1[ks], a1[mm], 0, 0, 0);
    }
}

__global__ __launch_bounds__(1024, 4)
void mpnn_one_kernel(const float* __restrict__ node, const int* __restrict__ eidx,
                     const float* __restrict__ Wm1, const float* __restrict__ bm1,
                     const float* __restrict__ Wm2, const float* __restrict__ bm2,
                     const float* __restrict__ Wu1, const float* __restrict__ bu1,
                     const float* __restrict__ Wu2, const float* __restrict__ bu2,
                     const float* __restrict__ gamma_, const float* __restrict__ beta_,
                     float* __restrict__ out) {
  __shared__ __align__(16) char L[L_BYTES];
  char* Xb   = L + XB_OFF;
  char* bufP = L + BP_OFF;
  char* bufQ = L + BQ_OFF;
  int*  csrL = (int*)(L + CSRL_OFF);
  int*  offsL= (int*)(L + OFFL_OFF);
  float (*bias)[HH] = (float(*)[HH])(L + BIAS_OFF);
  int*  scr  = (int*)(L + SCR_OFF);
  int*  edg   = scr;               // 2*EE = 3240
  int*  rankS = scr + 2 * EE;      // EE
  int*  cntC  = scr + 3 * EE;      // NCHK*NN = 2106
  int*  scanS = cntC + 2106;       // 128
  int*  wsumS = scanS + 128;       // 2
  float* xout = (float*)L;         // alias Xb+bufP (dead by GEMM D)

  const int tid  = threadIdx.x;
  const int lane = tid & 63;
  const int wave = tid >> 6;                 // 0..15
  const int b    = blockIdx.x;
  const int nt0  = wave & 7;
  const int rbase = (wave >> 3) * 48;        // M-half
  const int erow = (lane >> 4) * 4;
  const int ecol = lane & 15;
  const int C    = nt0 * 16 + ecol;

  // ---- GEMM A B-frags: issue global loads + convert before staging ----
  bf16x8 BA0[4], BA1[4];
  loadB4G(Wm1, nt0, lane, BA0);
  loadB4G(Wm1 + HH * HH, nt0, lane, BA1);

  // ---- stage Xb (swizzled bf16), edges, biases; zero cnt ----
  {
    const float4* nf4 = (const float4*)(node + (size_t)b * NN * HH);
    float4 v0 = nf4[tid];
    float4 v1 = nf4[tid + 1024];
    const bool has2 = tid < (2592 - 2048);
    float4 v2 = has2 ? nf4[tid + 2048] : make_float4(0.f, 0.f, 0.f, 0.f);
    {
      const int r = tid >> 5, c = (tid & 31) * 4;
      uint2 pv; pv.x = f2b2(v0.x, v0.y); pv.y = f2b2(v0.z, v0.w);
      *(uint2*)(Xb + swzu(r, c * 2)) = pv;
    }
    {
      const int i = tid + 1024, r = i >> 5, c = (i & 31) * 4;
      uint2 pv; pv.x = f2b2(v1.x, v1.y); pv.y = f2b2(v1.z, v1.w);
      *(uint2*)(Xb + swzu(r, c * 2)) = pv;
    }
    if (has2) {
      const int i = tid + 2048, r = i >> 5, c = (i & 31) * 4;
      uint2 pv; pv.x = f2b2(v2.x, v2.y); pv.y = f2b2(v2.z, v2.w);
      *(uint2*)(Xb + swzu(r, c * 2)) = pv;
    }
    if (tid < (MPAD - NN) * 16) {            // zero pad rows 81..95
      const int r = NN + tid / 16, m = tid % 16;
      ushort8v z = {0,0,0,0,0,0,0,0};
      *(ushort8v*)(Xb + swzu(r, m * 16)) = z;
    }
    for (int i = tid; i < 2 * EE; i += 1024) edg[i] = eidx[i];
    for (int i = tid; i < NCHK * NN; i += 1024) cntC[i] = 0;
    if (tid < HH) {
      bias[0][tid] = bm1[tid];  bias[1][tid] = bm2[tid];
      bias[2][tid] = bu1[tid];  bias[3][tid] = bu2[tid];
      bias[4][tid] = gamma_[tid]; bias[5][tid] = beta_[tid];
    }
  }
  __syncthreads();  // B0

  // ---- CSR counts via ballot match-masks (deterministic, stable) ----
  for (int c = wave; c < NCHK; c += 16) {
    const int e = c * 64 + lane;
    const bool ok = (e < EE);
    const int t = ok ? edg[EE + e] : -1;
    unsigned long long mymask = 0;
#pragma unroll
    for (int i = 0; i < 64; ++i) {
      const int ti = __shfl(t, i);
      const unsigned long long bal = __ballot(t == ti);
      if (i == lane) mymask = bal;
    }
    if (ok) {
      const int rank = __popcll(mymask & ((1ull << lane) - 1ull));
      rankS[e] = rank;
      if (rank == 0) cntC[c * NN + t] = __popcll(mymask);
    }
  }
  __syncthreads();  // B1

  // ---- totals + wave-local prefix scan ----
  int s_tot = 0;
  if (tid < 128) {
    if (tid < NN) {
#pragma unroll
      for (int c = 0; c < NCHK; ++c) s_tot += cntC[c * NN + tid];
    }
    int inc = s_tot;
    const int l = tid & 63;
#pragma unroll
    for (int d = 1; d < 64; d <<= 1) {
      int u = __shfl_up(inc, d);
      if (l >= d) inc += u;
    }
    scanS[tid] = inc;
    if (l == 63) wsumS[tid >> 6] = inc;
  }
  __syncthreads();  // B2

  // ---- combine scan, offs, per-chunk bases ----
  if (tid < 128) {
    const int inc = scanS[tid] + ((tid >> 6) ? wsumS[0] : 0);
    if (tid < NN) {
      const int off0 = inc - s_tot;
      offsL[tid] = off0;
      int run = off0;
#pragma unroll
      for (int c = 0; c < NCHK; ++c) {
        const int tmp = cntC[c * NN + tid];
        cntC[c * NN + tid] = run;
        run += tmp;
      }
    }
    if (tid == NN - 1) offsL[NN] = inc;
  }
  __syncthreads();  // B3

  // ---- scatter CSR (quick), then GEMM A in the same phase ----
  for (int e = tid; e < EE; e += 1024) {
    const int t = edg[EE + e];
    csrL[cntC[(e >> 6) * NN + t] + rankS[e]] = edg[e];
  }

  // ---- GEMM A: P -> bufP ; Q' = Q + bm1 -> bufQ ----
  {
    f32x4 accP[3], accQ[3];
#pragma unroll
    for (int mm = 0; mm < 3; ++mm) { accP[mm] = (f32x4)0.f; accQ[mm] = (f32x4)0.f; }
    gemm3x2(Xb, rbase, BA0, BA1, lane, accP, accQ);
#pragma unroll
    for (int mm = 0; mm < 3; ++mm)
#pragma unroll
      for (int rg = 0; rg < 4; ++rg) {
        const int R = rbase + mm * 16 + erow + rg;
        const unsigned byte = swzu(R, C * 2);
        const bool ok = (R < NN);
        *(unsigned short*)(bufP + byte) = ok ? f2b(accP[mm][rg]) : (unsigned short)0;
        *(unsigned short*)(bufQ + byte) = ok ? f2b(accQ[mm][rg] + bias[0][C]) : (unsigned short)0;
      }
  }
  // issue Wm2 B-frags now; latency hides under agg
  bf16x8 BB[4];
  loadB4G(Wm2, nt0, lane, BB);
  __syncthreads();  // B4

  // ---- edge aggregation (x4 unrolled): Hsum[t] = sum relu(P[s]+Q'[t]) -> bufQ
  {
    const int lb = lane * 4;
    for (int t = wave; t < NN; t += 16) {
      const unsigned qbyte = swzu(t, lb);
      const unsigned pq = *(const unsigned*)(bufQ + qbyte);
      const float q0 = b2f((unsigned short)(pq & 0xffff));
      const float q1 = b2f((unsigned short)(pq >> 16));
      float h0 = 0.f, h1 = 0.f, g0 = 0.f, g1 = 0.f;
      int e = offsL[t];
      const int o1 = offsL[t + 1];
      for (; e + 4 <= o1; e += 4) {
        const int s0 = csrL[e], s1 = csrL[e + 1], s2 = csrL[e + 2], s3 = csrL[e + 3];
        const unsigned p0 = *(const unsigned*)(bufP + swzu(s0, lb));
        const unsigned p1 = *(const unsigned*)(bufP + swzu(s1, lb));
        const unsigned p2 = *(const unsigned*)(bufP + swzu(s2, lb));
        const unsigned p3 = *(const unsigned*)(bufP + swzu(s3, lb));
        h0 += fmaxf(b2f((unsigned short)(p0 & 0xffff)) + q0, 0.f);
        h1 += fmaxf(b2f((unsigned short)(p0 >> 16))    + q1, 0.f);
        g0 += fmaxf(b2f((unsigned short)(p1 & 0xffff)) + q0, 0.f);
        g1 += fmaxf(b2f((unsigned short)(p1 >> 16))    + q1, 0.f);
        h0 += fmaxf(b2f((unsigned short)(p2 & 0xffff)) + q0, 0.f);
        h1 += fmaxf(b2f((unsigned short)(p2 >> 16))    + q1, 0.f);
        g0 += fmaxf(b2f((unsigned short)(p3 & 0xffff)) + q0, 0.f);
        g1 += fmaxf(b2f((unsigned short)(p3 >> 16))    + q1, 0.f);
      }
      for (; e < o1; ++e) {
        const int s = csrL[e];
        const unsigned pp = *(const unsigned*)(bufP + swzu(s, lb));
        h0 += fmaxf(b2f((unsigned short)(pp & 0xffff)) + q0, 0.f);
        h1 += fmaxf(b2f((unsigned short)(pp >> 16))    + q1, 0.f);
      }
      h0 += g0; h1 += g1;
      const unsigned hv = (unsigned)f2b(h0) | ((unsigned)f2b(h1) << 16);
      *(unsigned*)(bufQ + qbyte) = hv;
    }
  }
  __syncthreads();  // B5

  // ---- GEMM B: agg = (Hsum@Wm2 + deg*bm2)/max(deg,1) -> bufP ----
  {
    f32x4 acc[3];
#pragma unroll
    for (int mm = 0; mm < 3; ++mm) acc[mm] = (f32x4)0.f;
    gemm3(bufQ, rbase, BB, lane, acc);
#pragma unroll
    for (int mm = 0; mm < 3; ++mm)
#pragma unroll
      for (int rg = 0; rg < 4; ++rg) {
        const int R = rbase + mm * 16 + erow + rg;
        float v = 0.f;
        if (R < NN) {
          const int dg = offsL[R + 1] - offsL[R];
          const float inv = (dg > 0) ? 1.f / (float)dg : 1.f;
          v = (acc[mm][rg] + (float)dg * bias[1][C]) * inv;
        }
        *(unsigned short*)(bufP + swzu(R, C * 2)) = f2b(v);
      }
  }
  __syncthreads();  // B6

  // ---- GEMM C: h2 = relu(Xb@Wu1t + agg@Wu1b + bu1) -> bufQ ----
  {
    bf16x8 BC0[4], BC1[4];
    loadB4G(Wu1, nt0, lane, BC0);
    loadB4G(Wu1 + HH * HH, nt0, lane, BC1);
    f32x4 acc[3];
#pragma unroll
    for (int mm = 0; mm < 3; ++mm) acc[mm] = (f32x4)0.f;
    gemm3(Xb,   rbase, BC0, lane, acc);
    gemm3(bufP, rbase, BC1, lane, acc);
#pragma unroll
    for (int mm = 0; mm < 3; ++mm)
#pragma unroll
      for (int rg = 0; rg < 4; ++rg) {
        const int R = rbase + mm * 16 + erow + rg;
        const float v = (R < NN) ? fmaxf(acc[mm][rg] + bias[2][C], 0.f) : 0.f;
        *(unsigned short*)(bufQ + swzu(R, C * 2)) = f2b(v);
      }
  }
  __syncthreads();  // B7  (Xb, bufP dead past this point)

  // ---- GEMM D: x = resid + h2@Wu2 + bu2 -> xout (aliases Xb+bufP) ----
  {
    bf16x8 BD[4];
    loadB4G(Wu2, nt0, lane, BD);
    float resid[3][4];
    const float* nodeB = node + (size_t)b * NN * HH;
#pragma unroll
    for (int mm = 0; mm < 3; ++mm)
#pragma unroll
      for (int rg = 0; rg < 4; ++rg) {
        const int R = rbase + mm * 16 + erow + rg;
        resid[mm][rg] = (R < NN) ? nodeB[R * HH + C] : 0.f;
      }
    f32x4 acc[3];
#pragma unroll
    for (int mm = 0; mm < 3; ++mm) acc[mm] = (f32x4)0.f;
    gemm3(bufQ, rbase, BD, lane, acc);
#pragma unroll
    for (int mm = 0; mm < 3; ++mm)
#pragma unroll
      for (int rg = 0; rg < 4; ++rg) {
        const int R = rbase + mm * 16 + erow + rg;
        if (R < NN) xout[R * HH + C] = resid[mm][rg] + acc[mm][rg] + bias[3][C];
      }
  }
  __syncthreads();  // B8

  // ---- LayerNorm (6-row unrolled) + store ----
  {
    float x0[6], x1[6], mu[6], rstd[6];
#pragma unroll
    for (int k = 0; k < 6; ++k) {
      const int r = wave + 16 * k;
      const int rr = (r < NN) ? r : 0;
      x0[k] = xout[rr * HH + lane]; x1[k] = xout[rr * HH + lane + 64];
    }
#pragma unroll
    for (int k = 0; k < 6; ++k) {
      float s = x0[k] + x1[k];
#pragma unroll
      for (int off = 32; off; off >>= 1) s += __shfl_xor(s, off);
      mu[k] = s * (1.f / 128.f);
    }
#pragma unroll
    for (int k = 0; k < 6; ++k) {
      const float d0 = x0[k] - mu[k], d1 = x1[k] - mu[k];
      float v = d0 * d0 + d1 * d1;
#pragma unroll
      for (int off = 32; off; off >>= 1) v += __shfl_xor(v, off);
      rstd[k] = rsqrtf(v * (1.f / 128.f) + 1e-5f);
    }
#pragma unroll
    for (int k = 0; k < 6; ++k) {
      const int r = wave + 16 * k;
      if (r < NN) {
        const float d0 = x0[k] - mu[k], d1 = x1[k] - mu[k];
        const size_t o = ((size_t)b * NN + r) * HH;
        out[o + lane]      = d0 * rstd[k] * bias[4][lane]      + bias[5][lane];
        out[o + lane + 64] = d1 * rstd[k] * bias[4][lane + 64] + bias[5][lane + 64];
      }
    }
  }
}

extern "C" void kernel_launch(void* const* d_in, const int* in_sizes, int n_in,
                              void* d_out, int out_size, void* d_ws, size_t ws_size,
                              hipStream_t stream) {
  (void)in_sizes; (void)n_in; (void)out_size; (void)d_ws; (void)ws_size;
  const float* node  = (const float*)d_in[0];
  const int*   eidx  = (const int*)  d_in[1];
  const float* Wm1   = (const float*)d_in[2];
  const float* bm1   = (const float*)d_in[3];
  const float* Wm2   = (const float*)d_in[4];
  const float* bm2   = (const float*)d_in[5];
  const float* Wu1   = (const float*)d_in[6];
  const float* bu1   = (const float*)d_in[7];
  const float* Wu2   = (const float*)d_in[8];
  const float* bu2   = (const float*)d_in[9];
  const float* gamma_= (const float*)d_in[10];
  const float* beta_ = (const float*)d_in[11];
  float* outp = (float*)d_out;

  hipLaunchKernelGGL(mpnn_one_kernel, dim3(256), dim3(1024), 0, stream,
                     node, eidx, Wm1, bm1, Wm2, bm2, Wu1, bu1, Wu2, bu2,
                     gamma_, beta_, outp);
}

// Round 11
// 39.798 us; speedup vs baseline: 1.1573x; 1.1573x over previous
//
#include <hip/hip_runtime.h>

// Fused MPNN layer, B=256, N=81, H=128, E=1620 — MFMA fp16 (packed-VALU agg).
//   P = X @ Wm1[:H],  Q' = X @ Wm1[H:] + bm1
//   Hsum[t] = sum_{e: tgt=t} relu(P[src_e] + Q'[t])
//   Folded:  agg@Wu1b = (Hsum@Wc)*inv_deg + 1[deg>0]*bc,  Wc=Wm2@Wu1b, bc=bm2@Wu1b
//   h2 = relu(X@Wu1t + (Hsum@Wc)*inv + s*bc + bu1)
//   x  = X + h2 @ Wu2 + bu2 ;  out = LayerNorm(x)*gamma + beta
// Setup (grid 13 x 1024): blocks 0-7 pack {Wm1t,Wm1b,Wu1t,Wu2} to fp16 frag
//   order; block 8 ballot-CSR; blocks 9-12 Wc (fp32) -> fp16 pack, bs0 also bc.
// Main (grid 256, 1024 thr = 16 waves): whole layer per batch in LDS.
//   fp16 MFMA + v_pk_add/max_f16 aggregation.

#define NN 81
#define HH 128
#define EE 1620
#define NCHK 26                         // ceil(EE/64)
#define MPAD 96
#define WB_BYTES 196608                 // 6 * 16384 ushorts (slot4 unused)
#define OFFS_OFF (WB_BYTES)             // int offs[82]
#define CSR_OFF  (OFFS_OFF + 82 * 4)    // int csr[1620]
#define BC_OFF   (CSR_OFF + EE * 4)     // float bc[128]
#define WS_NEED  (BC_OFF + HH * 4)

typedef _Float16 f16x8 __attribute__((ext_vector_type(8)));
typedef __fp16   h16x2 __attribute__((ext_vector_type(2)));   // builtin's type
typedef __attribute__((ext_vector_type(8))) unsigned short ushort8v;
typedef __attribute__((ext_vector_type(4))) float f32x4;

__device__ __forceinline__ unsigned short f2h(float f) {
  union { _Float16 h; unsigned short u; } v; v.h = (_Float16)f; return v.u;
}
__device__ __forceinline__ unsigned f2h2(float x, float y) {   // v_cvt_pkrtz
  union { h16x2 h; unsigned u; } v;
  v.h = __builtin_amdgcn_cvt_pkrtz(x, y);
  return v.u;
}
__device__ __forceinline__ unsigned pk_add(unsigned a, unsigned b) {
  unsigned r; asm("v_pk_add_f16 %0, %1, %2" : "=v"(r) : "v"(a), "v"(b)); return r;
}
__device__ __forceinline__ unsigned pk_relu(unsigned a) {
  unsigned r; asm("v_pk_max_f16 %0, %1, %2" : "=v"(r) : "v"(a), "v"(0u)); return r;
}
__device__ __forceinline__ unsigned swzu(int r, int laneb) {
  return ((unsigned)(r * 256 + laneb)) ^ ((unsigned)((r & 7) << 4));
}

// ---------------- setup kernel ------------------------------------------------
__global__ __launch_bounds__(1024)
void setup_kernel(const float* __restrict__ Wm1, const float* __restrict__ Wm2,
                  const float* __restrict__ Wu1, const float* __restrict__ Wu2,
                  const float* __restrict__ bm2, const int* __restrict__ eidx,
                  char* __restrict__ ws) {
  __shared__ __align__(16) char arena[81920];
  const int tid = threadIdx.x;

  if (blockIdx.x < 8) {
    // pack 4 source mats to fp16 frag order: 4 mats * 8 nt * 4 ks * 64 lanes
    const int gid = blockIdx.x * 1024 + tid;
    const int lane = gid & 63;
    const int t = gid >> 6;
    const int ks = t & 3, nt = (t >> 2) & 7, mat = t >> 5;
    const float* src;
    int slot;
    if (mat == 0)      { src = Wm1;           slot = 0; }
    else if (mat == 1) { src = Wm1 + HH * HH; slot = 1; }
    else if (mat == 2) { src = Wu1;           slot = 3; }
    else               { src = Wu2;           slot = 5; }
    const int c = nt * 16 + (lane & 15);
    const int k0 = ks * 32 + (lane >> 4) * 8;
    f16x8 pv;
#pragma unroll
    for (int j = 0; j < 8; ++j) pv[j] = (_Float16)src[(k0 + j) * HH + c];
    *(f16x8*)((unsigned short*)ws + (size_t)slot * 16384 + (((nt * 4 + ks) * 64) + lane) * 8) = pv;
    return;
  }

  if (blockIdx.x == 8) {
    // deterministic CSR via ballot match-masks (stable counting sort)
    int* srcE  = (int*)arena;            // EE
    int* tgtE  = srcE + EE;              // EE
    int* rankS = tgtE + EE;              // EE
    int* cntC  = rankS + EE;             // NCHK*NN
    int* tot   = cntC + NCHK * NN;       // NN
    int* scanS = tot + NN;               // 128
    int* wsumS = scanS + 128;            // 2
    int* offsS = wsumS + 2;              // NN+1
    for (int i = tid; i < NCHK * NN; i += 1024) cntC[i] = 0;
    for (int i = tid; i < 2 * EE; i += 1024) srcE[i] = eidx[i];
    __syncthreads();
    const int lane = tid & 63, wv = tid >> 6;
    for (int c = wv; c < NCHK; c += 16) {
      const int e = c * 64 + lane;
      const bool ok = (e < EE);
      const int t = ok ? tgtE[e] : -1;
      unsigned long long mymask = 0;
#pragma unroll
      for (int i = 0; i < 64; ++i) {
        const int ti = __shfl(t, i);
        const unsigned long long bal = __ballot(t == ti);
        if (i == lane) mymask = bal;
      }
      if (ok) {
        const int rank = __popcll(mymask & ((1ull << lane) - 1ull));
        rankS[e] = rank;
        if (rank == 0) cntC[c * NN + t] = __popcll(mymask);
      }
    }
    __syncthreads();
    if (tid < NN) {
      int s = 0;
#pragma unroll
      for (int c = 0; c < NCHK; ++c) s += cntC[c * NN + tid];
      tot[tid] = s;
    }
    __syncthreads();
    if (tid < 128) {
      const int l = tid & 63, w = tid >> 6;
      int inc = (tid < NN) ? tot[tid] : 0;
#pragma unroll
      for (int d = 1; d < 64; d <<= 1) {
        int u = __shfl_up(inc, d);
        if (l >= d) inc += u;
      }
      scanS[tid] = inc;
      if (l == 63) wsumS[w] = inc;
    }
    __syncthreads();
    if (tid < 128) {
      const int w = tid >> 6;
      const int inc = scanS[tid] + (w ? wsumS[0] : 0);
      if (tid < NN) offsS[tid] = inc - tot[tid];
      if (tid == NN - 1) offsS[NN] = inc;
    }
    __syncthreads();
    if (tid < NN) {
      int run = offsS[tid];
#pragma unroll
      for (int c = 0; c < NCHK; ++c) {
        const int tmp = cntC[c * NN + tid];
        cntC[c * NN + tid] = run;
        run += tmp;
      }
    }
    __syncthreads();
    int* wofs = (int*)(ws + OFFS_OFF);
    int* wcsr = (int*)(ws + CSR_OFF);
    for (int i = tid; i <= NN; i += 1024) wofs[i] = offsS[i];
    for (int e = tid; e < EE; e += 1024) {
      const int t = tgtE[e];
      wcsr[cntC[(e >> 6) * NN + t] + rankS[e]] = srcE[e];
    }
    return;
  }

  // blocks 9-12: Wc = Wm2 @ Wu1b, rows [32*bs,32*bs+32); pack slot 2; bs0: bc
  {
    const int bs = blockIdx.x - 9;
    float* WuL = (float*)arena;
    float* WmL = WuL + HH * HH;
    const float* Wu1b = Wu1 + HH * HH;
    float4* WuL4 = (float4*)WuL;
    const float4* src4 = (const float4*)Wu1b;
    for (int i = tid; i < HH * HH / 4; i += 1024) WuL4[i] = src4[i];
    const float4* wm4 = (const float4*)(Wm2 + bs * 32 * HH);
    float4* WmL4 = (float4*)WmL;
    if (tid < 32 * HH / 4) WmL4[tid] = wm4[tid];
    __syncthreads();
    const int kk = tid >> 5;
    const int k  = bs * 32 + kk;
    const int cg = tid & 31;
    f32x4 acc = (f32x4)0.f;
    for (int j = 0; j < HH; ++j) {
      const float a = WmL[kk * HH + j];
      const float4 w = WuL4[j * 32 + cg];
      acc[0] += a * w.x; acc[1] += a * w.y; acc[2] += a * w.z; acc[3] += a * w.w;
    }
    unsigned short* dst = (unsigned short*)ws;
#pragma unroll
    for (int q = 0; q < 4; ++q) {
      const int c = cg * 4 + q;
      const int nt = c >> 4;
      const int l = (((k & 31) >> 3) << 4) | (c & 15);
      dst[(size_t)2 * 16384 + (((nt * 4 + bs) * 64) + l) * 8 + (k & 7)] = f2h(acc[q]);
    }
    if (bs == 0 && tid < HH) {
      float s = 0.f;
      for (int j = 0; j < HH; ++j) s += bm2[j] * WuL[j * HH + tid];
      ((float*)(ws + BC_OFF))[tid] = s;
    }
  }
}

// ---------------- MFMA helpers (fp16, per wave: 3 M-tiles x 1 N-tile) --------
__device__ __forceinline__ void loadB(const unsigned short* Wp, int nt0, int lane,
                                      f16x8 (&Bf)[4]) {
#pragma unroll
  for (int ks = 0; ks < 4; ++ks)
    Bf[ks] = *(const f16x8*)(Wp + ((nt0 * 4 + ks) * 64 + lane) * 8);
}

__device__ __forceinline__ void gemm3(const char* Ab, const f16x8 (&Bf)[4],
                                      int lane, int mt0, f32x4 (&acc)[3]) {
  const int rl = lane & 15;
  const int kb = (lane >> 4) * 16;
  const unsigned swz = (unsigned)((rl & 7) << 4);
#pragma unroll
  for (int ks = 0; ks < 4; ++ks)
#pragma unroll
    for (int mm = 0; mm < 3; ++mm) {
      const int r = (mt0 + mm) * 16 + rl;
      const unsigned byte = (unsigned)(r * 256) + (((unsigned)(ks * 64 + kb)) ^ swz);
      f16x8 a = *(const f16x8*)(Ab + byte);
      acc[mm] = __builtin_amdgcn_mfma_f32_16x16x32_f16(a, Bf[ks], acc[mm], 0, 0, 0);
    }
}

__device__ __forceinline__ void gemm3x2(const char* Ab,
                                        const f16x8 (&B0)[4], const f16x8 (&B1)[4],
                                        int lane, int mt0,
                                        f32x4 (&a0)[3], f32x4 (&a1)[3]) {
  const int rl = lane & 15;
  const int kb = (lane >> 4) * 16;
  const unsigned swz = (unsigned)((rl & 7) << 4);
#pragma unroll
  for (int ks = 0; ks < 4; ++ks)
#pragma unroll
    for (int mm = 0; mm < 3; ++mm) {
      const int r = (mt0 + mm) * 16 + rl;
      const unsigned byte = (unsigned)(r * 256) + (((unsigned)(ks * 64 + kb)) ^ swz);
      f16x8 a = *(const f16x8*)(Ab + byte);
      a0[mm] = __builtin_amdgcn_mfma_f32_16x16x32_f16(a, B0[ks], a0[mm], 0, 0, 0);
      a1[mm] = __builtin_amdgcn_mfma_f32_16x16x32_f16(a, B1[ks], a1[mm], 0, 0, 0);
    }
}

// dual-A (T = Hsum@Wc, U = Xb@Wu1t)
__device__ __forceinline__ void gemm3_2A(const char* A0, const char* A1,
                                         const f16x8 (&B0)[4], const f16x8 (&B1)[4],
                                         int lane, int mt0,
                                         f32x4 (&a0)[3], f32x4 (&a1)[3]) {
  const int rl = lane & 15;
  const int kb = (lane >> 4) * 16;
  const unsigned swz = (unsigned)((rl & 7) << 4);
#pragma unroll
  for (int ks = 0; ks < 4; ++ks)
#pragma unroll
    for (int mm = 0; mm < 3; ++mm) {
      const int r = (mt0 + mm) * 16 + rl;
      const unsigned byte = (unsigned)(r * 256) + (((unsigned)(ks * 64 + kb)) ^ swz);
      f16x8 x0 = *(const f16x8*)(A0 + byte);
      a0[mm] = __builtin_amdgcn_mfma_f32_16x16x32_f16(x0, B0[ks], a0[mm], 0, 0, 0);
      f16x8 x1 = *(const f16x8*)(A1 + byte);
      a1[mm] = __builtin_amdgcn_mfma_f32_16x16x32_f16(x1, B1[ks], a1[mm], 0, 0, 0);
    }
}

__global__ __launch_bounds__(1024, 4)
void mpnn_fp16_kernel(const float* __restrict__ node,
                      const float* __restrict__ bm1,
                      const float* __restrict__ bu1, const float* __restrict__ bu2,
                      const float* __restrict__ gamma_, const float* __restrict__ beta_,
                      const char* __restrict__ ws,
                      float* __restrict__ out) {
  __shared__ float X[NN][HH];                 // fp32 for residual + LN
  __shared__ unsigned short XbS[MPAD * HH];   // swizzled fp16
  __shared__ unsigned short bufPS[MPAD * HH]; // P -> h2
  __shared__ unsigned short bufQS[MPAD * HH]; // Q' -> Hsum
  __shared__ int   csrL[EE];
  __shared__ int   offsL[NN + 1];
  __shared__ float bias[6][HH];               // bm1,bc,bu1,bu2,gamma,beta
  char* Xb   = (char*)XbS;
  char* bufP = (char*)bufPS;
  char* bufQ = (char*)bufQS;

  const int tid  = threadIdx.x;
  const int lane = tid & 63;
  const int wave = tid >> 6;     // 0..15
  const int b    = blockIdx.x;

  const unsigned short* wpk = (const unsigned short*)ws;
  const int* wofs = (const int*)(ws + OFFS_OFF);
  const int* wcsr = (const int*)(ws + CSR_OFF);
  const float* wbc = (const float*)(ws + BC_OFF);

  // wave tile map: 16 waves = 8 N-tiles x 2 M-halves (3 M-tiles each)
  const int nt0 = wave & 7;
  const int mt0 = 3 * (wave >> 3);
  const int erow = (lane >> 4) * 4;
  const int ecol = lane & 15;
  const int C    = nt0 * 16 + ecol;

  // ---- GEMM-A B-frag preload (global, independent of LDS staging) ----
  f16x8 BA0[4], BA1[4];
  loadB(wpk, nt0, lane, BA0);
  loadB(wpk + 16384, nt0, lane, BA1);

  // ---- stage: X fp32 + Xb fp16 (swizzled), csr/offs, biases ----
  {
    const float4* nf4 = (const float4*)(node + (size_t)b * NN * HH);
    const int i2 = tid + 2048;
    const bool has2 = (i2 < NN * HH / 4);     // 2592 float4 total
    float4 v0 = nf4[tid];
    float4 v1 = nf4[tid + 1024];
    float4 v2 = has2 ? nf4[i2] : make_float4(0.f, 0.f, 0.f, 0.f);
#pragma unroll
    for (int k = 0; k < 3; ++k) {
      const int i = tid + k * 1024;
      if (k == 2 && !has2) break;
      const float4 v = (k == 0) ? v0 : (k == 1) ? v1 : v2;
      const int r = i >> 5, c = (i & 31) * 4;
      *(float4*)&X[r][c] = v;
      uint2 pv; pv.x = f2h2(v.x, v.y); pv.y = f2h2(v.z, v.w);
      *(uint2*)(Xb + swzu(r, c * 2)) = pv;
    }
    if (tid < (MPAD - NN) * 16) {   // zero pad rows 81..95
      const int r = NN + tid / 16, m = tid % 16;
      ushort8v z = {0,0,0,0,0,0,0,0};
      *(ushort8v*)(Xb + swzu(r, m * 16)) = z;
    }
    for (int i = tid; i < EE; i += 1024) csrL[i] = wcsr[i];
    if (tid < NN + 1) offsL[tid] = wofs[tid];
    if (tid < HH) {
      bias[0][tid] = bm1[tid];  bias[1][tid] = wbc[tid];
      bias[2][tid] = bu1[tid];  bias[3][tid] = bu2[tid];
      bias[4][tid] = gamma_[tid]; bias[5][tid] = beta_[tid];
    }
  }
  __syncthreads();

  // ---- GEMM A: P = Xb@Wm1t -> bufP ; Q' = Xb@Wm1b + bm1 -> bufQ ----
  {
    f32x4 accP[3], accQ[3];
#pragma unroll
    for (int mm = 0; mm < 3; ++mm) { accP[mm] = (f32x4)0.f; accQ[mm] = (f32x4)0.f; }
    gemm3x2(Xb, BA0, BA1, lane, mt0, accP, accQ);
#pragma unroll
    for (int mm = 0; mm < 3; ++mm)
#pragma unroll
      for (int rg = 0; rg < 4; ++rg) {
        const int R = (mt0 + mm) * 16 + erow + rg;
        const unsigned byte = swzu(R, C * 2);
        const bool ok = (R < NN);
        *(unsigned short*)(bufP + byte) = ok ? f2h(accP[mm][rg]) : (unsigned short)0;
        *(unsigned short*)(bufQ + byte) = ok ? f2h(accQ[mm][rg] + bias[0][C]) : (unsigned short)0;
      }
  }
  __syncthreads();

  // ---- edge aggregation, packed fp16 (x4 unrolled):
  //      Hsum[t] = sum relu(P[s] + Q'[t]) -> bufQ
  {
    const int lb = lane * 4;
    for (int t = wave; t < NN; t += 16) {
      const unsigned qbyte = swzu(t, lb);
      const unsigned q = *(const unsigned*)(bufQ + qbyte);
      unsigned h = 0u, g = 0u;                 // two packed fp16 accumulators
      int e = offsL[t];
      const int o1 = offsL[t + 1];
      for (; e + 4 <= o1; e += 4) {
        const int s0 = csrL[e], s1 = csrL[e + 1], s2 = csrL[e + 2], s3 = csrL[e + 3];
        const unsigned p0 = *(const unsigned*)(bufP + swzu(s0, lb));
        const unsigned p1 = *(const unsigned*)(bufP + swzu(s1, lb));
        const unsigned p2 = *(const unsigned*)(bufP + swzu(s2, lb));
        const unsigned p3 = *(const unsigned*)(bufP + swzu(s3, lb));
        h = pk_add(h, pk_relu(pk_add(p0, q)));
        g = pk_add(g, pk_relu(pk_add(p1, q)));
        h = pk_add(h, pk_relu(pk_add(p2, q)));
        g = pk_add(g, pk_relu(pk_add(p3, q)));
      }
      for (; e < o1; ++e) {
        const int s = csrL[e];
        const unsigned pp = *(const unsigned*)(bufP + swzu(s, lb));
        h = pk_add(h, pk_relu(pk_add(pp, q)));
      }
      h = pk_add(h, g);
      *(unsigned*)(bufQ + qbyte) = h;
    }
  }
  __syncthreads();

  // ---- GEMM BC: T = Hsum@Wc ; U = Xb@Wu1t ;
  //      h2 = relu(U + T*inv_deg + s*bc + bu1) -> bufP ----
  {
    f16x8 BW[4], BU[4];
    loadB(wpk + 2 * 16384, nt0, lane, BW);
    loadB(wpk + 3 * 16384, nt0, lane, BU);
    f32x4 accT[3], accU[3];
#pragma unroll
    for (int mm = 0; mm < 3; ++mm) { accT[mm] = (f32x4)0.f; accU[mm] = (f32x4)0.f; }
    gemm3_2A(bufQ, Xb, BW, BU, lane, mt0, accT, accU);
#pragma unroll
    for (int mm = 0; mm < 3; ++mm)
#pragma unroll
      for (int rg = 0; rg < 4; ++rg) {
        const int R = (mt0 + mm) * 16 + erow + rg;
        float v = 0.f;
        if (R < NN) {
          const int dg = offsL[R + 1] - offsL[R];
          const float inv = (dg > 0) ? 1.f / (float)dg : 1.f;
          const float sf  = (dg > 0) ? 1.f : 0.f;
          v = fmaxf(accU[mm][rg] + accT[mm][rg] * inv + sf * bias[1][C] + bias[2][C], 0.f);
        }
        *(unsigned short*)(bufP + swzu(R, C * 2)) = f2h(v);
      }
  }
  __syncthreads();

  // ---- GEMM D: x = X + h2@Wu2 + bu2 (in place into X fp32) ----
  {
    f16x8 BD[4];
    loadB(wpk + 5 * 16384, nt0, lane, BD);
    f32x4 acc[3];
#pragma unroll
    for (int mm = 0; mm < 3; ++mm) acc[mm] = (f32x4)0.f;
    gemm3(bufP, BD, lane, mt0, acc);
#pragma unroll
    for (int mm = 0; mm < 3; ++mm)
#pragma unroll
      for (int rg = 0; rg < 4; ++rg) {
        const int R = (mt0 + mm) * 16 + erow + rg;
        if (R < NN) X[R][C] += acc[mm][rg] + bias[3][C];
      }
  }
  __syncthreads();

  // ---- LayerNorm per row + store ----
  for (int r = wave; r < NN; r += 16) {
    const float x0 = X[r][lane], x1 = X[r][lane + 64];
    float s = x0 + x1;
#pragma unroll
    for (int off = 32; off; off >>= 1) s += __shfl_xor(s, off);
    const float mu = s * (1.f / 128.f);
    const float d0 = x0 - mu, d1 = x1 - mu;
    float v = d0 * d0 + d1 * d1;
#pragma unroll
    for (int off = 32; off; off >>= 1) v += __shfl_xor(v, off);
    const float rstd = rsqrtf(v * (1.f / 128.f) + 1e-5f);
    const size_t o = ((size_t)b * NN + r) * HH;
    out[o + lane]      = d0 * rstd * bias[4][lane]      + bias[5][lane];
    out[o + lane + 64] = d1 * rstd * bias[4][lane + 64] + bias[5][lane + 64];
  }
}

// ================= fp32 fallback (known-good, used only if ws too small) =====
__device__ __forceinline__ void gemm_acc_f32(const float (*A)[HH], const float* __restrict__ Wg,
                                             int c, int row0, int nr, float (&acc)[41]) {
  float w[8];
#pragma unroll
  for (int j = 0; j < 8; ++j) w[j] = Wg[j * HH + c];
  for (int k0 = 0; k0 < HH; k0 += 8) {
    float wn[8];
    if (k0 + 8 < HH) {
#pragma unroll
      for (int j = 0; j < 8; ++j) wn[j] = Wg[(k0 + 8 + j) * HH + c];
    }
#pragma unroll
    for (int i = 0; i < 41; ++i) {
      if (i < nr) {
        const float4 a0 = *(const float4*)&A[row0 + i][k0];
        const float4 a1 = *(const float4*)&A[row0 + i][k0 + 4];
        acc[i] += a0.x * w[0] + a0.y * w[1] + a0.z * w[2] + a0.w * w[3]
                + a1.x * w[4] + a1.y * w[5] + a1.z * w[6] + a1.w * w[7];
      }
    }
#pragma unroll
    for (int j = 0; j < 8; ++j) w[j] = wn[j];
  }
}

__global__ __launch_bounds__(256, 1)
void mpnn_fused_kernel(const float* __restrict__ node, const int* __restrict__ eidx,
                       const float* __restrict__ Wm1, const float* __restrict__ bm1,
                       const float* __restrict__ Wm2, const float* __restrict__ bm2,
                       const float* __restrict__ Wu1, const float* __restrict__ bu1,
                       const float* __restrict__ Wu2, const float* __restrict__ bu2,
                       const float* __restrict__ gamma_, const float* __restrict__ beta_,
                       float* __restrict__ out) {
  __shared__ float X[NN][HH];
  __shared__ float Pb[NN][HH];
  __shared__ float Qb[NN][HH];
  __shared__ int   edg[2 * EE];
  __shared__ int   csr[EE];
  __shared__ int   offs[NN + 1];
  __shared__ int   cnt3[3][NN];
  __shared__ int   base3[3][NN];
  __shared__ float biases[6][HH];

  const int tid  = threadIdx.x;
  const int lane = tid & 63;
  const int wave = tid >> 6;
  const int b    = blockIdx.x;

  {
    const float4* nf4 = (const float4*)(node + (size_t)b * NN * HH);
    float4* X4 = (float4*)&X[0][0];
    for (int i = tid; i < NN * HH / 4; i += 256) X4[i] = nf4[i];
    for (int i = tid; i < 2 * EE; i += 256) edg[i] = eidx[i];
    if (tid < HH) {
      biases[0][tid] = bm1[tid]; biases[1][tid] = bm2[tid];
      biases[2][tid] = bu1[tid]; biases[3][tid] = bu2[tid];
      biases[4][tid] = gamma_[tid]; biases[5][tid] = beta_[tid];
    }
  }
  __syncthreads();
  if (tid < 3 * NN) {
    const int t = tid % NN, ch = tid / NN;
    const int e0 = ch * 540, e1 = e0 + 540;
    int cnt = 0;
    for (int e = e0; e < e1; ++e) cnt += (edg[EE + e] == t);
    cnt3[ch][t] = cnt;
  }
  __syncthreads();
  if (tid == 0) {
    int run = 0;
    for (int t = 0; t < NN; ++t) {
      offs[t] = run;
      base3[0][t] = run;
      base3[1][t] = base3[0][t] + cnt3[0][t];
      base3[2][t] = base3[1][t] + cnt3[1][t];
      run = base3[2][t] + cnt3[2][t];
    }
    offs[NN] = run;
  }
  __syncthreads();
  if (tid < 3 * NN) {
    const int t = tid % NN, ch = tid / NN;
    const int e0 = ch * 540, e1 = e0 + 540;
    int pos = base3[ch][t];
    for (int e = e0; e < e1; ++e)
      if (edg[EE + e] == t) csr[pos++] = edg[e];
  }
  __syncthreads();

  const int c    = ((wave & 1) << 6) | lane;
  const int row0 = (wave >> 1) ? 41 : 0;
  const int nr   = (wave >> 1) ? 40 : 41;

  {
    float acc[41];
#pragma unroll
    for (int i = 0; i < 41; ++i) acc[i] = 0.f;
    gemm_acc_f32(X, Wm1, c, row0, nr, acc);
#pragma unroll
    for (int i = 0; i < 41; ++i) if (i < nr) Pb[row0 + i][c] = acc[i];
  }
  {
    float acc[41];
#pragma unroll
    for (int i = 0; i < 41; ++i) acc[i] = 0.f;
    gemm_acc_f32(X, Wm1 + HH * HH, c, row0, nr, acc);
#pragma unroll
    for (int i = 0; i < 41; ++i) if (i < nr) Qb[row0 + i][c] = acc[i];
  }
  __syncthreads();

  for (int t = wave; t < NN; t += 4) {
    const int o0 = offs[t], o1 = offs[t + 1];
    const float q0 = Qb[t][lane]      + biases[0][lane];
    const float q1 = Qb[t][lane + 64] + biases[0][lane + 64];
    float h0 = 0.f, h1 = 0.f;
    for (int e = o0; e < o1; ++e) {
      const int s = csr[e];
      h0 += fmaxf(Pb[s][lane]      + q0, 0.f);
      h1 += fmaxf(Pb[s][lane + 64] + q1, 0.f);
    }
    Qb[t][lane]      = h0;
    Qb[t][lane + 64] = h1;
  }
  __syncthreads();

  {
    float acc[41];
#pragma unroll
    for (int i = 0; i < 41; ++i) acc[i] = 0.f;
    gemm_acc_f32(Qb, Wm2, c, row0, nr, acc);
#pragma unroll
    for (int i = 0; i < 41; ++i) if (i < nr) {
      const int r = row0 + i;
      const float d = (float)(offs[r + 1] - offs[r]);
      Pb[r][c] = (acc[i] + d * biases[1][c]) * (1.f / fmaxf(d, 1.f));
    }
  }
  __syncthreads();

  {
    float acc[41];
#pragma unroll
    for (int i = 0; i < 41; ++i) acc[i] = 0.f;
    gemm_acc_f32(X,  Wu1,           c, row0, nr, acc);
    gemm_acc_f32(Pb, Wu1 + HH * HH, c, row0, nr, acc);
#pragma unroll
    for (int i = 0; i < 41; ++i) if (i < nr)
      Qb[row0 + i][c] = fmaxf(acc[i] + biases[2][c], 0.f);
  }
  __syncthreads();

  {
    float acc[41];
#pragma unroll
    for (int i = 0; i < 41; ++i) acc[i] = 0.f;
    gemm_acc_f32(Qb, Wu2, c, row0, nr, acc);
#pragma unroll
    for (int i = 0; i < 41; ++i) if (i < nr) {
      const int r = row0 + i;
      X[r][c] = X[r][c] + acc[i] + biases[3][c];
    }
  }
  __syncthreads();

  for (int r = wave; r < NN; r += 4) {
    const float x0 = X[r][lane], x1 = X[r][lane + 64];
    float s = x0 + x1;
#pragma unroll
    for (int off = 32; off; off >>= 1) s += __shfl_xor(s, off);
    const float mu = s * (1.f / 128.f);
    const float d0 = x0 - mu, d1 = x1 - mu;
    float v = d0 * d0 + d1 * d1;
#pragma unroll
    for (int off = 32; off; off >>= 1) v += __shfl_xor(v, off);
    const float rstd = rsqrtf(v * (1.f / 128.f) + 1e-5f);
    const size_t o = ((size_t)b * NN + r) * HH;
    out[o + lane]      = d0 * rstd * biases[4][lane]      + biases[5][lane];
    out[o + lane + 64] = d1 * rstd * biases[4][lane + 64] + biases[5][lane + 64];
  }
}

extern "C" void kernel_launch(void* const* d_in, const int* in_sizes, int n_in,
                              void* d_out, int out_size, void* d_ws, size_t ws_size,
                              hipStream_t stream) {
  (void)in_sizes; (void)n_in; (void)out_size;
  const float* node  = (const float*)d_in[0];
  const int*   eidx  = (const int*)  d_in[1];
  const float* Wm1   = (const float*)d_in[2];
  const float* bm1   = (const float*)d_in[3];
  const float* Wm2   = (const float*)d_in[4];
  const float* bm2   = (const float*)d_in[5];
  const float* Wu1   = (const float*)d_in[6];
  const float* bu1   = (const float*)d_in[7];
  const float* Wu2   = (const float*)d_in[8];
  const float* bu2   = (const float*)d_in[9];
  const float* gamma_= (const float*)d_in[10];
  const float* beta_ = (const float*)d_in[11];
  float* outp = (float*)d_out;

  if (ws_size >= (size_t)WS_NEED) {
    char* ws = (char*)d_ws;
    hipLaunchKernelGGL(setup_kernel, dim3(13), dim3(1024), 0, stream,
                       Wm1, Wm2, Wu1, Wu2, bm2, eidx, ws);
    hipLaunchKernelGGL(mpnn_fp16_kernel, dim3(256), dim3(1024), 0, stream,
                       node, bm1, bu1, bu2, gamma_, beta_, ws, outp);
  } else {
    hipLaunchKernelGGL(mpnn_fused_kernel, dim3(256), dim3(256), 0, stream,
                       node, eidx, Wm1, bm1, Wm2, bm2, Wu1, bu1, Wu2, bu2,
                       gamma_, beta_, outp);
  }
}